// Round 14
// baseline (133.585 us; speedup 1.0000x reference)
//
#include <hip/hip_runtime.h>
#include <hip/hip_bf16.h>

#define NFFT   4194304
#define NMODES 2
#define NTAPS  101
#define NVALID (NFFT - NTAPS + 1)   // 4194204
#define N0     (NTAPS / 2)          // 50

constexpr int BLOCK = 256;                          // 4 waves
constexpr int TILE  = 2048;                         // output samples per tile
constexpr int NTT   = (NVALID + TILE - 1) / TILE;   // 2048 tiles
constexpr int TPB   = 2;                            // tiles per block (pipelined pairs)
constexpr int NB    = NTT / TPB;                    // 1024 blocks
constexpr int WIN   = 2176;                         // staged P samples (max read idx 2151)
constexpr int NCH   = WIN / 2;                      // 1088 16B chunks per x array
constexpr int NM    = 15;                           // banded MFMA accumulation steps
constexpr int TBW   = 272;                          // compact B-table words

// LDS word layout: xaR[0..4351] | xbR[4352..8703] | Pl[8704..10879] | Bt[10880..11151]
constexpr int OXB = 4352;
constexpr int OPL = 8704;
constexpr int OBT = 10880;
constexpr int LWORDS = 11152;                       // 44608 B -> 3 blocks/CU

typedef __attribute__((ext_vector_type(8)))  short short8;
typedef __attribute__((ext_vector_type(16))) float float16;

static __device__ __forceinline__ unsigned short f2bf(float x) {
    __hip_bfloat16 h = __float2bfloat16(x);
    return *reinterpret_cast<unsigned short*>(&h);
}
static __device__ __forceinline__ unsigned pk(float e0, float e1) {
    return (unsigned)f2bf(e0) | ((unsigned)f2bf(e1) << 16);
}
// XOR word bits 2..4 with word bits 5..7: bijective, preserves aligned 4-word groups,
// spreads 64B-stride accesses across banks (residual 2-way = free).
static __device__ __forceinline__ int swz(int s) {
    return s ^ (((s >> 5) & 7) << 2);
}
// HBM -> LDS direct (16B/lane, no VGPR round trip). LDS dest must be linear:
// lane's pointer == wave-uniform base + lane*16 (holds for c = uniform + lane).
static __device__ __forceinline__ void gl16(const float4* g, unsigned* l) {
    __builtin_amdgcn_global_load_lds(
        (const __attribute__((address_space(1))) void*)g,
        (__attribute__((address_space(3))) void*)l, 16, 0, 0);
}

__global__ __launch_bounds__(BLOCK, 3) void nl_kernel(
    const float* __restrict__ xa,   // d_in[0] big stream (A = xr)
    const float* __restrict__ xb,   // d_in[1] big stream (B = xi)
    const float* __restrict__ W,  const float* __restrict__ b,
    const float* __restrict__ power, unsigned* __restrict__ out)
{
    __shared__ __align__(16) unsigned lds[LWORDS];
    unsigned* const xaR = lds;
    unsigned* const xbR = lds + OXB;
    unsigned* const Pl  = lds + OPL;
    unsigned* const Bt  = lds + OBT;

    const int tid  = threadIdx.x;
    const int lane = tid & 63;
    const int wid  = tid >> 6;
    const int colc = lane & 31;      // B/C column = (c_s<<1)|o ; also A row index
    const int h    = lane >> 5;      // k half: k = 8h + e
    const int cs   = colc >> 1;      // fine shift 0..15
    const int o    = colc & 1;       // output mode
    const int r    = colc;           // A row

    const float4* __restrict__ xa4 = reinterpret_cast<const float4*>(xa); // 2 samples
    const float4* __restrict__ xb4 = reinterpret_cast<const float4*>(xb);

    const int tbase = blockIdx.x * TPB;

    // Raw chunk c = tid + 256k is staged by thread tid and P-read ONLY by thread tid
    // -> raw buffer is thread-private: single buffer, overwrite after own P-compute.
    #define STAGE(wt) {                                                             \
        const int ts2 = (wt) * (TILE / 2);                                          \
        _Pragma("unroll")                                                           \
        for (int k = 0; k < 4; ++k) {                                               \
            const int c  = tid + 256 * k;            /* chunk = uniform + lane */   \
            const int cc = min(ts2 + c, NFFT / 2 - 1);                              \
            gl16(xa4 + cc, &xaR[4 * c]);                                            \
            gl16(xb4 + cc, &xbR[4 * c]);                                            \
        }                                                                           \
        if (tid < 64) {                              /* chunks 1024..1087 */        \
            const int c  = tid + 1024;                                              \
            const int cc = min((wt) * (TILE / 2) + c, NFFT / 2 - 1);                \
            gl16(xa4 + cc, &xaR[4 * c]);                                            \
            gl16(xb4 + cc, &xbR[4 * c]);                                            \
        }                                                                           \
    }

    // ---- prologue: stage tile 0; build Bt while the DMA flies ----
    STAGE(tbase)
    {
        const float4* __restrict__ Wt = reinterpret_cast<const float4*>(W);
        #pragma unroll
        for (int idx = tid; idx < TBW; idx += BLOCK) {
            const int t  = (idx >> 1) - 15;
            const int oo = idx & 1;
            const bool ok = (unsigned)t <= 100u;
            const float4 w = Wt[ok ? t : 0];
            Bt[idx] = ok ? pk(oo ? w.y : w.x, oo ? w.w : w.z) : 0u;
        }
    }

    const float bo   = o ? b[1] : b[0];
    const float coef = 0.066268f * exp10f(power[0] * 0.1f);
    const int bbase  = ((4 * h - cs + 15) << 1) | o;
    const int cb     = wid * 512;

    #pragma unroll 1
    for (int t = 0; t < TPB; ++t) {
        const int wt     = tbase + t;
        const int wstart = wt * TILE;

        // Wait for THIS tile's stage loads. In-order vmcnt retirement: after tile t's
        // stage (8-10 wave-ops) the younger ops are 32 epilogue loads + 16 stores of
        // tile t-1, so <=16 outstanding guarantees all stage loads retired.
        if (t == 0) { asm volatile("s_waitcnt vmcnt(0)" ::: "memory"); }
        else       { asm volatile("s_waitcnt vmcnt(16)" ::: "memory"); }
        __builtin_amdgcn_sched_barrier(0);

        // ---- P = xa^2 + xb^2 -> bf16x2 swizzled Pl (thread-private raw reads) ----
        #pragma unroll
        for (int k = 0; k < 5; ++k) {
            const int tp = tid + 256 * k;            // chunk index
            if (k < 4 || tp < NCH) {
                const float4 a = *reinterpret_cast<const float4*>(&xaR[4 * tp]);
                const float4 c = *reinterpret_cast<const float4*>(&xbR[4 * tp]);
                const int g = wstart + 2 * tp;       // even; g,g+1 valid together
                unsigned u0 = 0u, u1 = 0u;
                if (g < NFFT) {
                    u0 = pk(a.x * a.x + c.x * c.x, a.y * a.y + c.y * c.y);
                    u1 = pk(a.z * a.z + c.z * c.z, a.w * a.w + c.w * c.w);
                }
                *reinterpret_cast<uint2*>(&Pl[swz(2 * tp)]) = make_uint2(u0, u1);
            }
        }

        // ---- issue NEXT tile's stage NOW (own raw chunks already consumed) ----
        if (t + 1 < TPB) STAGE(wt + 1)
        __builtin_amdgcn_sched_barrier(0);

        // Raw barrier (no vmcnt drain): Pl writes visible to all waves.
        asm volatile("s_waitcnt lgkmcnt(0)" ::: "memory");
        __builtin_amdgcn_s_barrier();
        __builtin_amdgcn_sched_barrier(0);

        // ---- 15 x (b128 A + 4x b32 B + 32x32x16 MFMA) ----
        float16 acc = {};
        uint4 areg[4];                // 4-deep A prefetch pipe (static idx post-unroll)
        #pragma unroll
        for (int m = 0; m < 4; ++m)
            areg[m] = *reinterpret_cast<const uint4*>(&Pl[swz(cb + 16 * r + 8 * m + 4 * h)]);
        #pragma unroll
        for (int m = 0; m < NM; ++m) {
            uint4 bq;
            bq.x = Bt[bbase + 16 * m + 0];
            bq.y = Bt[bbase + 16 * m + 2];
            bq.z = Bt[bbase + 16 * m + 4];
            bq.w = Bt[bbase + 16 * m + 6];
            acc = __builtin_amdgcn_mfma_f32_32x32x16_bf16(
                      __builtin_bit_cast(short8, areg[m & 3]),
                      __builtin_bit_cast(short8, bq), acc, 0, 0, 0);
            if (m + 4 < NM)
                areg[m & 3] = *reinterpret_cast<const uint4*>(
                                  &Pl[swz(cb + 16 * r + 8 * (m + 4) + 4 * h)]);
        }

        // Raw barrier: all waves done reading Pl(t) before next iter's P writes.
        asm volatile("s_waitcnt lgkmcnt(0)" ::: "memory");
        __builtin_amdgcn_s_barrier();
        __builtin_amdgcn_sched_barrier(0);

        // ---- epilogue: direct from accumulators; x from GLOBAL (L2-hot) ----
        // (raw LDS is being overwritten by STAGE(t+1) -> must not read it here)
        // C/D: col = lane&31, row = (reg&3) + 8*(reg>>2) + 4*(lane>>5).
        if (wt != NTT - 1) {                          // full tile: branch-free
            #pragma unroll
            for (int j = 0; j < 16; ++j) {
                const int row = (j & 3) + 8 * (j >> 2) + 4 * h;
                const int n   = wstart + cb + 16 * row + cs;
                const float Ax = xa[(n + N0) * 2 + o];
                const float Bx = xb[(n + N0) * 2 + o];
                float sn, cn;
                __sincosf((acc[j] + bo) * coef, &sn, &cn);
                __builtin_nontemporal_store(pk(Bx * cn - Ax * sn, Ax * cn + Bx * sn),
                                            &out[n * 2 + o]);
            }
        } else {                                      // global last tile: guarded
            #pragma unroll
            for (int j = 0; j < 16; ++j) {
                const int row = (j & 3) + 8 * (j >> 2) + 4 * h;
                const int n   = wstart + cb + 16 * row + cs;
                if (n < NVALID) {
                    const float Ax = xa[(n + N0) * 2 + o];
                    const float Bx = xb[(n + N0) * 2 + o];
                    float sn, cn;
                    __sincosf((acc[j] + bo) * coef, &sn, &cn);
                    __builtin_nontemporal_store(pk(Bx * cn - Ax * sn, Ax * cn + Bx * sn),
                                                &out[n * 2 + o]);
                }
            }
        }
    }
    #undef STAGE
}

extern "C" void kernel_launch(void* const* d_in, const int* in_sizes, int n_in,
                              void* d_out, int out_size, void* d_ws, size_t ws_size,
                              hipStream_t stream) {
    // Bind by size (robust): big arrays = x streams, 404 = W, 2 = b, 1 = power.
    const float* big[2] = {nullptr, nullptr};
    const float* W = nullptr; const float* b = nullptr; const float* power = nullptr;
    int nbig = 0;
    for (int i = 0; i < n_in; ++i) {
        const float* p = (const float*)d_in[i];
        const int sz = in_sizes[i];
        if (sz == NFFT * NMODES)       { if (nbig < 2) big[nbig++] = p; }
        else if (sz == NTAPS * NMODES * NMODES) { W = p; }
        else if (sz == NMODES)         { b = p; }
        else if (sz == 1)              { power = p; }
    }

    unsigned* out = (unsigned*)d_out;
    nl_kernel<<<NB, BLOCK, 0, stream>>>(big[0], big[1], W, b, power, out);
}

// Round 15
// 113.755 us; speedup vs baseline: 1.1743x; 1.1743x over previous
//
#include <hip/hip_runtime.h>
#include <hip/hip_bf16.h>

#define NFFT   4194304
#define NMODES 2
#define NTAPS  101
#define NVALID (NFFT - NTAPS + 1)   // 4194204
#define N0     (NTAPS / 2)          // 50

constexpr int BLOCK = 256;                          // 4 waves
constexpr int TILE  = 2048;                         // output samples per block
constexpr int NT    = (NVALID + TILE - 1) / TILE;   // 2048 blocks
constexpr int WIN   = 2176;                         // staged P samples (max read idx 2151)
constexpr int NM    = 15;                           // banded MFMA accumulation steps
constexpr int TBW   = 272;                          // compact B-table words

// LDS word layout: xaR[0..4351] | xbR[4352..8703] | Pl[8704..10879] | Bt[10880..11151]
constexpr int OXB = 4352;
constexpr int OPL = 8704;
constexpr int OBT = 10880;
constexpr int LWORDS = 11152;                       // 44608 B -> 3 blocks/CU

typedef __attribute__((ext_vector_type(8)))  short short8;
typedef __attribute__((ext_vector_type(16))) float float16;

static __device__ __forceinline__ unsigned short f2bf(float x) {
    __hip_bfloat16 h = __float2bfloat16(x);
    return *reinterpret_cast<unsigned short*>(&h);
}
static __device__ __forceinline__ unsigned pk(float e0, float e1) {
    return (unsigned)f2bf(e0) | ((unsigned)f2bf(e1) << 16);
}
// XOR word bits 2..4 with word bits 5..7: bijective, preserves aligned 4-word groups,
// spreads 64B-stride accesses across banks (residual 2-way = free).
static __device__ __forceinline__ int swz(int s) {
    return s ^ (((s >> 5) & 7) << 2);
}
// HBM -> LDS direct (16B/lane, no VGPR round trip). LDS dest must be linear:
// lane's pointer == wave-uniform base + lane*16 (holds for c = uniform + lane).
static __device__ __forceinline__ void gl16(const float4* g, unsigned* l) {
    __builtin_amdgcn_global_load_lds(
        (const __attribute__((address_space(1))) void*)g,
        (__attribute__((address_space(3))) void*)l, 16, 0, 0);
}

__global__ __launch_bounds__(BLOCK, 3) void nl_kernel(
    const float* __restrict__ xa,   // d_in[0] big stream (A = xr)
    const float* __restrict__ xb,   // d_in[1] big stream (B = xi)
    const float* __restrict__ W,  const float* __restrict__ b,
    const float* __restrict__ power, unsigned* __restrict__ out)
{
    __shared__ __align__(16) unsigned lds[LWORDS];
    unsigned* const xaR = lds;
    unsigned* const xbR = lds + OXB;
    unsigned* const Pl  = lds + OPL;
    unsigned* const Bt  = lds + OBT;

    const int tid  = threadIdx.x;
    const int lane = tid & 63;
    const int wid  = tid >> 6;
    const int colc = lane & 31;      // B/C column = (c_s<<1)|o ; also A row index
    const int h    = lane >> 5;      // k half: k = 8h + e
    const int cs   = colc >> 1;      // fine shift 0..15
    const int o    = colc & 1;       // output mode
    const int r    = colc;           // A row

    const int tile_start = blockIdx.x * TILE;
    const int ts2        = tile_start >> 1;

    const float4* __restrict__ xa4 = reinterpret_cast<const float4*>(xa); // 2 samples
    const float4* __restrict__ xb4 = reinterpret_cast<const float4*>(xb);

    // ---- 0) compact B table FIRST (so its loads retire before staging issues,
    //         keeping the stage vmcnt arithmetic exact) ----
    {
        const float4* __restrict__ Wt = reinterpret_cast<const float4*>(W);
        #pragma unroll
        for (int idx = tid; idx < TBW; idx += BLOCK) {
            const int t  = (idx >> 1) - 15;
            const int oo = idx & 1;
            const bool ok = (unsigned)t <= 100u;
            const float4 w = Wt[ok ? t : 0];
            Bt[idx] = ok ? pk(oo ? w.y : w.x, oo ? w.w : w.z) : 0u;
        }
    }
    __builtin_amdgcn_sched_barrier(0);

    // ---- 1) issue ALL stage DMA: 5 pairs/thread, uniform (pair 4 is a benign
    //         4-way duplicate of chunks 1024..1087 -> same addr, same data) ----
    // Chunk c staged by thread tid and P-read ONLY by thread tid.
    #pragma unroll
    for (int k = 0; k < 5; ++k) {
        const int c  = (k < 4) ? (tid + 256 * k) : (1024 + (tid & 63));
        const int cc = min(ts2 + c, NFFT / 2 - 1);   // clamp OOB (zeroed in P-compute)
        gl16(xa4 + cc, &xaR[4 * c]);                 // op 2k
        gl16(xb4 + cc, &xbR[4 * c]);                 // op 2k+1
    }

    // ---- 2) consume pair-by-pair with counted vmcnt: P-compute of pair k needs
    //         only ops 0..2k+1 retired -> wait vmcnt(8-2k). Later loads stay in
    //         flight under the earlier pairs' compute (no full drain). ----
    #define PSTEP(K, CNT) {                                                         \
        asm volatile("s_waitcnt vmcnt(" CNT ")" ::: "memory");                      \
        __builtin_amdgcn_sched_barrier(0);                                          \
        const int tp = ((K) < 4) ? (tid + 256 * (K)) : (1024 + (tid & 63));         \
        const float4 a = *reinterpret_cast<const float4*>(&xaR[4 * tp]);            \
        const float4 c = *reinterpret_cast<const float4*>(&xbR[4 * tp]);            \
        const int g = tile_start + 2 * tp;           /* even; g,g+1 together */     \
        unsigned u0 = 0u, u1 = 0u;                                                  \
        if (g < NFFT) {                                                             \
            u0 = pk(a.x * a.x + c.x * c.x, a.y * a.y + c.y * c.y);                  \
            u1 = pk(a.z * a.z + c.z * c.z, a.w * a.w + c.w * c.w);                  \
        }                                                                           \
        *reinterpret_cast<uint2*>(&Pl[swz(2 * tp)]) = make_uint2(u0, u1);           \
    }
    PSTEP(0, "8")
    PSTEP(1, "6")
    PSTEP(2, "4")
    PSTEP(3, "2")
    PSTEP(4, "0")
    #undef PSTEP

    __syncthreads();     // vmcnt already 0; makes Pl/Bt/raw visible block-wide

    // ---- 3) per-wave 512-sample chunk: 15 x (b128 A + 4x b32 B + MFMA) ----
    const int cb    = wid * 512;
    const int bbase = ((4 * h - cs + 15) << 1) | o;
    float16 acc = {};
    uint4 areg[4];                    // 4-deep A prefetch pipe (static idx post-unroll)
    #pragma unroll
    for (int m = 0; m < 4; ++m)
        areg[m] = *reinterpret_cast<const uint4*>(&Pl[swz(cb + 16 * r + 8 * m + 4 * h)]);
    #pragma unroll
    for (int m = 0; m < NM; ++m) {
        uint4 bq;
        bq.x = Bt[bbase + 16 * m + 0];
        bq.y = Bt[bbase + 16 * m + 2];
        bq.z = Bt[bbase + 16 * m + 4];
        bq.w = Bt[bbase + 16 * m + 6];
        acc = __builtin_amdgcn_mfma_f32_32x32x16_bf16(
                  __builtin_bit_cast(short8, areg[m & 3]),
                  __builtin_bit_cast(short8, bq), acc, 0, 0, 0);
        if (m + 4 < NM)
            areg[m & 3] = *reinterpret_cast<const uint4*>(
                              &Pl[swz(cb + 16 * r + 8 * (m + 4) + 4 * h)]);
    }

    // ---- 4) epilogue: direct from accumulators; x re-read from LDS raw copy ----
    // C/D: col = lane&31, row = (reg&3) + 8*(reg>>2) + 4*(lane>>5).
    // local x word = 2*(cb + 16*row + cs + N0) + o, max 4195 < 4352: always staged.
    const float bo   = o ? b[1] : b[0];
    const float coef = 0.066268f * exp10f(power[0] * 0.1f);
    const float* __restrict__ xaF = reinterpret_cast<const float*>(xaR);
    const float* __restrict__ xbF = reinterpret_cast<const float*>(xbR);

    if (blockIdx.x != NT - 1) {                       // full tile: branch-free
        #pragma unroll
        for (int j = 0; j < 16; ++j) {
            const int row = (j & 3) + 8 * (j >> 2) + 4 * h;
            const int lw  = 2 * (cb + 16 * row + cs + N0) + o;
            const float Ax = xaF[lw];
            const float Bx = xbF[lw];
            float sn, cn;
            __sincosf((acc[j] + bo) * coef, &sn, &cn);
            const int n = tile_start + cb + 16 * row + cs;
            __builtin_nontemporal_store(pk(Bx * cn - Ax * sn, Ax * cn + Bx * sn),
                                        &out[n * 2 + o]);
        }
    } else {                                          // tail tile: guarded stores
        #pragma unroll
        for (int j = 0; j < 16; ++j) {
            const int row = (j & 3) + 8 * (j >> 2) + 4 * h;
            const int n   = tile_start + cb + 16 * row + cs;
            if (n < NVALID) {
                const int lw  = 2 * (cb + 16 * row + cs + N0) + o;
                const float Ax = xaF[lw];
                const float Bx = xbF[lw];
                float sn, cn;
                __sincosf((acc[j] + bo) * coef, &sn, &cn);
                __builtin_nontemporal_store(pk(Bx * cn - Ax * sn, Ax * cn + Bx * sn),
                                            &out[n * 2 + o]);
            }
        }
    }
}

extern "C" void kernel_launch(void* const* d_in, const int* in_sizes, int n_in,
                              void* d_out, int out_size, void* d_ws, size_t ws_size,
                              hipStream_t stream) {
    // Bind by size (robust): big arrays = x streams, 404 = W, 2 = b, 1 = power.
    const float* big[2] = {nullptr, nullptr};
    const float* W = nullptr; const float* b = nullptr; const float* power = nullptr;
    int nbig = 0;
    for (int i = 0; i < n_in; ++i) {
        const float* p = (const float*)d_in[i];
        const int sz = in_sizes[i];
        if (sz == NFFT * NMODES)       { if (nbig < 2) big[nbig++] = p; }
        else if (sz == NTAPS * NMODES * NMODES) { W = p; }
        else if (sz == NMODES)         { b = p; }
        else if (sz == 1)              { power = p; }
    }

    unsigned* out = (unsigned*)d_out;
    nl_kernel<<<NT, BLOCK, 0, stream>>>(big[0], big[1], W, b, power, out);
}